// Round 5
// baseline (329.616 us; speedup 1.0000x reference)
//
#include <hip/hip_runtime.h>
#include <math.h>

#define N_NODES 50000
#define N_EDGES 800000
#define N_FEAT 100
#define N_CLASSES 40
#define N_SLICES 8
#define SLICE_NODES 6250        // N_NODES / N_SLICES exactly
#define FILL_CHUNKS 256
#define FILL_EDGES_PER_CHUNK 3125  // N_EDGES / FILL_CHUNKS exactly
#define SCAN_T 1024
#define SCAN_CH 49              // 1024*49 = 50176 >= N_NODES

// ---------------- edge dtype detection ----------------
// flag pre-zeroed by memset; 0 = int64, 1 = int32.
// Read first N_EDGES slots as int64 (6.4MB = full int32 buffer, in-bounds both ways).
// If buffer is int32, a slot packs two ids -> >= N_NODES with p~1.

__global__ void k_detect(const long long* __restrict__ ei64, int* __restrict__ flag) {
    int e = blockIdx.x * blockDim.x + threadIdx.x;
    if (e >= N_EDGES) return;
    long long v = ei64[e];
    if (v < 0 || v >= N_NODES) *flag = 1;  // int32 evidence; all writers write 1
}

// ---------------- convert to packed u32 + degree count (fused) ----------------

__global__ void k_convert(const void* __restrict__ ei, const int* __restrict__ flag,
                          unsigned int* __restrict__ epack, int* __restrict__ deg) {
    int e = blockIdx.x * blockDim.x + threadIdx.x;
    if (e >= N_EDGES) return;
    unsigned int r, c;
    if (*flag == 0) {
        const long long* p = (const long long*)ei;
        r = (unsigned int)p[e];
        c = (unsigned int)p[N_EDGES + e];
    } else {
        const unsigned int* p = (const unsigned int*)ei;
        r = p[e];
        c = p[N_EDGES + e];
    }
    epack[e] = r | (c << 16);
    atomicAdd(&deg[c], 1);  // no return value used -> fire-and-forget
}

// ---------------- single-block scan: deg -> offs, cursor, dinv ----------------

__global__ void k_scan(const int* __restrict__ deg, int* __restrict__ offs,
                       int* __restrict__ cursor, float* __restrict__ dinv) {
    __shared__ int ssum[SCAN_T];
    int t = threadIdx.x;
    int lo = t * SCAN_CH;
    int hi = lo + SCAN_CH; if (hi > N_NODES) hi = N_NODES;
    int sum = 0;
    for (int i = lo; i < hi; ++i) sum += deg[i];
    ssum[t] = sum;
    __syncthreads();
    for (int off = 1; off < SCAN_T; off <<= 1) {
        int v = (t >= off) ? ssum[t - off] : 0;
        __syncthreads();
        ssum[t] += v;
        __syncthreads();
    }
    int run = t ? ssum[t - 1] : 0;  // exclusive base for this thread's range
    for (int i = lo; i < hi; ++i) {
        int d = deg[i];
        offs[i] = run;
        cursor[i] = run;
        dinv[i] = rsqrtf((float)d + 1.0f);  // +1 self-loop
        run += d;
    }
    if (t == 0) offs[N_NODES] = N_EDGES;
}

// ---------------- XCD-sliced CSR fill ----------------
// block -> (slice = bid % 8, chunk = bid / 8). bid%8 tracks the round-robin
// block->XCD mapping, so csr/cursor lines of a slice are dirtied by ONE XCD
// and coalesce in its L2 instead of 8 partial-line evictions per line.

__global__ void k_fill(const unsigned int* __restrict__ epack, const float* __restrict__ dinv,
                       int* __restrict__ cursor, uint2* __restrict__ csr) {
    int slice = blockIdx.x & (N_SLICES - 1);
    int chunk = blockIdx.x >> 3;
    unsigned int lo = slice * SLICE_NODES, hi = lo + SLICE_NODES;
    int e0 = chunk * FILL_EDGES_PER_CHUNK;
    int e1 = e0 + FILL_EDGES_PER_CHUNK;
    for (int e = e0 + threadIdx.x; e < e1; e += blockDim.x) {
        unsigned int p = epack[e];
        unsigned int c = p >> 16;
        if (c >= lo && c < hi) {
            unsigned int r = p & 0xffffu;
            int pos = atomicAdd(&cursor[c], 1);
            csr[pos] = make_uint2(r, __float_as_uint(dinv[r] * dinv[c]));
        }
    }
}

// ---------------- linear: y0 = x @ W (bias deferred) ----------------

__global__ void k_linear(const float* __restrict__ h, const float* __restrict__ W,
                         float* __restrict__ y) {
    __shared__ float4 Ws[N_CLASSES / 4][N_FEAT];  // 16 KB
    for (int i = threadIdx.x; i < N_FEAT * (N_CLASSES / 4); i += blockDim.x) {
        int k = i / (N_CLASSES / 4), c4 = i - k * (N_CLASSES / 4);
        Ws[c4][k] = ((const float4*)W)[i];
    }
    __syncthreads();
    int idx = blockIdx.x * blockDim.x + threadIdx.x;
    if (idx >= N_NODES * (N_CLASSES / 4)) return;
    int n = idx / (N_CLASSES / 4);
    int c4 = idx - n * (N_CLASSES / 4);
    const float* hr = h + n * N_FEAT;
    float4 s = {0.f, 0.f, 0.f, 0.f};
#pragma unroll
    for (int k = 0; k < N_FEAT; ++k) {
        float hv = hr[k];
        float4 w = Ws[c4][k];
        s.x += hv * w.x; s.y += hv * w.y; s.z += hv * w.z; s.w += hv * w.w;
    }
    ((float4*)y)[idx] = s;
}

// ---------------- pull-gather hop (optionally fused bias+log_softmax) ----------------

template <int F, bool LSM>
__global__ void k_gather(const int* __restrict__ offs, const uint2* __restrict__ csr,
                         const float* __restrict__ src, const float* __restrict__ dinv,
                         float* __restrict__ dst, const float* __restrict__ bias) {
    int wave = threadIdx.x >> 6;
    int lane = threadIdx.x & 63;
    int n = blockIdx.x * 4 + wave;
    if (n >= N_NODES) return;
    int s = offs[n], e = offs[n + 1];
    float acc0 = 0.0f, acc1 = 0.0f;
    if (lane < F) {
        float d = dinv[n];
        acc0 = d * d * src[n * F + lane];
    }
    int i = s;
    for (; i + 3 < e; i += 4) {
        uint2 e0 = csr[i], e1 = csr[i + 1], e2 = csr[i + 2], e3 = csr[i + 3];
        if (lane < F) {
            acc0 += __uint_as_float(e0.y) * src[e0.x * F + lane];
            acc1 += __uint_as_float(e1.y) * src[e1.x * F + lane];
            acc0 += __uint_as_float(e2.y) * src[e2.x * F + lane];
            acc1 += __uint_as_float(e3.y) * src[e3.x * F + lane];
        }
    }
    for (; i < e; ++i) {
        uint2 e0 = csr[i];
        if (lane < F) acc0 += __uint_as_float(e0.y) * src[e0.x * F + lane];
    }
    float acc = acc0 + acc1;
    if (!LSM) {
        if (lane < F) dst[n * F + lane] = acc;
    } else {
        float v = (lane < F) ? acc + bias[lane] : -INFINITY;
        float m = v;
#pragma unroll
        for (int off = 32; off; off >>= 1) m = fmaxf(m, __shfl_xor(m, off));
        float ex = (lane < F) ? __expf(v - m) : 0.0f;
        float ssum = ex;
#pragma unroll
        for (int off = 32; off; off >>= 1) ssum += __shfl_xor(ssum, off);
        float ls = logf(ssum);
        if (lane < F) dst[n * F + lane] = v - m - ls;
    }
}

// ---------------- launch ----------------

extern "C" void kernel_launch(void* const* d_in, const int* in_sizes, int n_in,
                              void* d_out, int out_size, void* d_ws, size_t ws_size,
                              hipStream_t stream) {
    const float* x = (const float*)d_in[0];
    const void* ei = d_in[1];                // [2, E], int32 or int64 (auto-detected)
    const float* W = (const float*)d_in[2];  // [F, C]
    const float* b = (const float*)d_in[3];  // [C]
    float* z = (float*)d_out;                // [N, C]

    // workspace layout (256B-aligned chunks)
    char* ws = (char*)d_ws;
    size_t o = 0;
    auto alloc = [&](size_t bytes) { char* p = ws + o; o += (bytes + 255) & ~(size_t)255; return p; };
    int*          flagdeg = (int*)alloc((N_NODES + 64) * 4);  // [flag | pad | deg]
    int*          flag    = flagdeg;
    int*          deg     = flagdeg + 64;
    unsigned int* epack   = (unsigned int*)alloc((size_t)N_EDGES * 4);
    float*        dinv    = (float*)alloc(N_NODES * 4);
    int*          offs    = (int*)alloc((N_NODES + 1) * 4);
    int*          cursor  = (int*)alloc(N_NODES * 4);
    uint2*        csr     = (uint2*)alloc((size_t)N_EDGES * 8);
    float*        y0      = (float*)alloc((size_t)N_NODES * N_CLASSES * 4);
    float*        h1      = (float*)alloc((size_t)N_NODES * N_CLASSES * 4);

    const int T = 256;
    auto blocks = [](long long total, int t) { return (int)((total + t - 1) / t); };

    // zero flag + deg in one memset
    hipMemsetAsync(flagdeg, 0, (N_NODES + 64) * 4, stream);

    // dtype detect + convert (degree count fused)
    k_detect<<<blocks(N_EDGES, T), T, 0, stream>>>((const long long*)ei, flag);
    k_convert<<<blocks(N_EDGES, T), T, 0, stream>>>(ei, flag, epack, deg);

    // single-block scan -> offs, cursor, dinv
    k_scan<<<1, SCAN_T, 0, stream>>>(deg, offs, cursor, dinv);

    // XCD-sliced CSR fill
    k_fill<<<FILL_CHUNKS * N_SLICES, T, 0, stream>>>(epack, dinv, cursor, csr);

    // y0 = x @ W  (W commutes with propagation; both hops F=40)
    k_linear<<<blocks((long long)N_NODES * (N_CLASSES / 4), T), T, 0, stream>>>(x, W, y0);

    // hop 1: h1 = A_hat @ y0
    k_gather<N_CLASSES, false><<<(N_NODES + 3) / 4, T, 0, stream>>>(offs, csr, y0, dinv, h1, b);
    // hop 2 fused with bias + log_softmax
    k_gather<N_CLASSES, true><<<(N_NODES + 3) / 4, T, 0, stream>>>(offs, csr, h1, dinv, z, b);
}

// Round 6
// 205.533 us; speedup vs baseline: 1.6037x; 1.6037x over previous
//
#include <hip/hip_runtime.h>
#include <math.h>

#define N_NODES 50000
#define N_EDGES 800000
#define N_FEAT 100
#define N_CLASSES 40
#define N_SLICES 8
#define SLICE_NODES 6250        // N_NODES / N_SLICES exactly
#define FILL_CHUNKS 256
#define FILL_EDGES_PER_CHUNK 3125  // N_EDGES / FILL_CHUNKS exactly
#define SCAN_BLK 256
#define N_SCAN_BLKS ((N_NODES + SCAN_BLK - 1) / SCAN_BLK)  // 196

// ---------------- edge dtype detection ----------------
// flag pre-zeroed by memset; 0 = int64, 1 = int32.
// Read first N_EDGES slots as int64 (6.4MB = full int32 buffer, in-bounds both ways).
// If buffer is int32, a slot packs two ids -> >= N_NODES with p~1.

__global__ void k_detect(const long long* __restrict__ ei64, int* __restrict__ flag) {
    int e = blockIdx.x * blockDim.x + threadIdx.x;
    if (e >= N_EDGES) return;
    long long v = ei64[e];
    if (v < 0 || v >= N_NODES) *flag = 1;  // int32 evidence; all writers write 1
}

// ---------------- convert to packed u32 + degree count (fused) ----------------

__global__ void k_convert(const void* __restrict__ ei, const int* __restrict__ flag,
                          unsigned int* __restrict__ epack, int* __restrict__ deg) {
    int e = blockIdx.x * blockDim.x + threadIdx.x;
    if (e >= N_EDGES) return;
    unsigned int r, c;
    if (*flag == 0) {
        const long long* p = (const long long*)ei;
        r = (unsigned int)p[e];
        c = (unsigned int)p[N_EDGES + e];
    } else {
        const unsigned int* p = (const unsigned int*)ei;
        r = p[e];
        c = p[N_EDGES + e];
    }
    epack[e] = r | (c << 16);
    atomicAdd(&deg[c], 1);  // no return value used -> fire-and-forget
}

// ---------------- 3-kernel exclusive scan: deg -> offs (+ dinv fused) ----------------

__global__ void k_scan1(const int* __restrict__ deg, int* __restrict__ offs,
                        int* __restrict__ sums, float* __restrict__ dinv) {
    __shared__ int s[SCAN_BLK];
    int i = blockIdx.x * SCAN_BLK + threadIdx.x;
    int v = (i < N_NODES) ? deg[i] : 0;
    if (i < N_NODES) dinv[i] = rsqrtf((float)v + 1.0f);  // +1 self-loop
    s[threadIdx.x] = v;
    __syncthreads();
    for (int off = 1; off < SCAN_BLK; off <<= 1) {
        int t = (threadIdx.x >= off) ? s[threadIdx.x - off] : 0;
        __syncthreads();
        s[threadIdx.x] += t;
        __syncthreads();
    }
    if (i < N_NODES) offs[i] = s[threadIdx.x] - v;  // exclusive
    if (threadIdx.x == SCAN_BLK - 1) sums[blockIdx.x] = s[SCAN_BLK - 1];
}

__global__ void k_scan2(int* __restrict__ sums) {
    __shared__ int s[SCAN_BLK];
    int v = (threadIdx.x < N_SCAN_BLKS) ? sums[threadIdx.x] : 0;
    s[threadIdx.x] = v;
    __syncthreads();
    for (int off = 1; off < SCAN_BLK; off <<= 1) {
        int t = (threadIdx.x >= off) ? s[threadIdx.x - off] : 0;
        __syncthreads();
        s[threadIdx.x] += t;
        __syncthreads();
    }
    if (threadIdx.x < N_SCAN_BLKS) sums[threadIdx.x] = s[threadIdx.x] - v;  // exclusive
}

__global__ void k_scan3(int* __restrict__ offs, const int* __restrict__ sums,
                        int* __restrict__ cursor) {
    int i = blockIdx.x * SCAN_BLK + threadIdx.x;
    if (i < N_NODES) {
        int o = offs[i] + sums[blockIdx.x];
        offs[i] = o;
        cursor[i] = o;
    }
    if (i == 0) offs[N_NODES] = N_EDGES;
}

// ---------------- XCD-sliced CSR fill ----------------
// block -> (slice = bid % 8, chunk = bid / 8). bid%8 tracks the round-robin
// block->XCD mapping, so csr/cursor lines of a slice are dirtied by ONE XCD
// and coalesce in its L2 instead of 8 partial-line evictions per line.

__global__ void k_fill(const unsigned int* __restrict__ epack, const float* __restrict__ dinv,
                       int* __restrict__ cursor, uint2* __restrict__ csr) {
    int slice = blockIdx.x & (N_SLICES - 1);
    int chunk = blockIdx.x >> 3;
    unsigned int lo = slice * SLICE_NODES, hi = lo + SLICE_NODES;
    int e0 = chunk * FILL_EDGES_PER_CHUNK;
    int e1 = e0 + FILL_EDGES_PER_CHUNK;
    for (int e = e0 + threadIdx.x; e < e1; e += blockDim.x) {
        unsigned int p = epack[e];
        unsigned int c = p >> 16;
        if (c >= lo && c < hi) {
            unsigned int r = p & 0xffffu;
            int pos = atomicAdd(&cursor[c], 1);
            csr[pos] = make_uint2(r, __float_as_uint(dinv[r] * dinv[c]));
        }
    }
}

// ---------------- linear: y0 = x @ W (bias deferred) ----------------

__global__ void k_linear(const float* __restrict__ h, const float* __restrict__ W,
                         float* __restrict__ y) {
    __shared__ float4 Ws[N_CLASSES / 4][N_FEAT];  // 16 KB
    for (int i = threadIdx.x; i < N_FEAT * (N_CLASSES / 4); i += blockDim.x) {
        int k = i / (N_CLASSES / 4), c4 = i - k * (N_CLASSES / 4);
        Ws[c4][k] = ((const float4*)W)[i];
    }
    __syncthreads();
    int idx = blockIdx.x * blockDim.x + threadIdx.x;
    if (idx >= N_NODES * (N_CLASSES / 4)) return;
    int n = idx / (N_CLASSES / 4);
    int c4 = idx - n * (N_CLASSES / 4);
    const float* hr = h + n * N_FEAT;
    float4 s = {0.f, 0.f, 0.f, 0.f};
#pragma unroll
    for (int k = 0; k < N_FEAT; ++k) {
        float hv = hr[k];
        float4 w = Ws[c4][k];
        s.x += hv * w.x; s.y += hv * w.y; s.z += hv * w.z; s.w += hv * w.w;
    }
    ((float4*)y)[idx] = s;
}

// ---------------- pull-gather hop (optionally fused bias+log_softmax) ----------------

template <int F, bool LSM>
__global__ void k_gather(const int* __restrict__ offs, const uint2* __restrict__ csr,
                         const float* __restrict__ src, const float* __restrict__ dinv,
                         float* __restrict__ dst, const float* __restrict__ bias) {
    int wave = threadIdx.x >> 6;
    int lane = threadIdx.x & 63;
    int n = blockIdx.x * 4 + wave;
    if (n >= N_NODES) return;
    int s = offs[n], e = offs[n + 1];
    float acc0 = 0.0f, acc1 = 0.0f;
    if (lane < F) {
        float d = dinv[n];
        acc0 = d * d * src[n * F + lane];
    }
    int i = s;
    for (; i + 3 < e; i += 4) {
        uint2 e0 = csr[i], e1 = csr[i + 1], e2 = csr[i + 2], e3 = csr[i + 3];
        if (lane < F) {
            acc0 += __uint_as_float(e0.y) * src[e0.x * F + lane];
            acc1 += __uint_as_float(e1.y) * src[e1.x * F + lane];
            acc0 += __uint_as_float(e2.y) * src[e2.x * F + lane];
            acc1 += __uint_as_float(e3.y) * src[e3.x * F + lane];
        }
    }
    for (; i < e; ++i) {
        uint2 e0 = csr[i];
        if (lane < F) acc0 += __uint_as_float(e0.y) * src[e0.x * F + lane];
    }
    float acc = acc0 + acc1;
    if (!LSM) {
        if (lane < F) dst[n * F + lane] = acc;
    } else {
        float v = (lane < F) ? acc + bias[lane] : -INFINITY;
        float m = v;
#pragma unroll
        for (int off = 32; off; off >>= 1) m = fmaxf(m, __shfl_xor(m, off));
        float ex = (lane < F) ? __expf(v - m) : 0.0f;
        float ssum = ex;
#pragma unroll
        for (int off = 32; off; off >>= 1) ssum += __shfl_xor(ssum, off);
        float ls = logf(ssum);
        if (lane < F) dst[n * F + lane] = v - m - ls;
    }
}

// ---------------- launch ----------------

extern "C" void kernel_launch(void* const* d_in, const int* in_sizes, int n_in,
                              void* d_out, int out_size, void* d_ws, size_t ws_size,
                              hipStream_t stream) {
    const float* x = (const float*)d_in[0];
    const void* ei = d_in[1];                // [2, E], int32 or int64 (auto-detected)
    const float* W = (const float*)d_in[2];  // [F, C]
    const float* b = (const float*)d_in[3];  // [C]
    float* z = (float*)d_out;                // [N, C]

    // workspace layout (256B-aligned chunks)
    char* ws = (char*)d_ws;
    size_t o = 0;
    auto alloc = [&](size_t bytes) { char* p = ws + o; o += (bytes + 255) & ~(size_t)255; return p; };
    int*          flagdeg = (int*)alloc((N_NODES + 64) * 4);  // [flag | pad | deg]
    int*          flag    = flagdeg;
    int*          deg     = flagdeg + 64;
    unsigned int* epack   = (unsigned int*)alloc((size_t)N_EDGES * 4);
    float*        dinv    = (float*)alloc(N_NODES * 4);
    int*          offs    = (int*)alloc((N_NODES + 1) * 4);
    int*          cursor  = (int*)alloc(N_NODES * 4);
    int*          sums    = (int*)alloc(SCAN_BLK * 4);
    uint2*        csr     = (uint2*)alloc((size_t)N_EDGES * 8);
    float*        y0      = (float*)alloc((size_t)N_NODES * N_CLASSES * 4);
    float*        h1      = (float*)alloc((size_t)N_NODES * N_CLASSES * 4);

    const int T = 256;
    auto blocks = [](long long total, int t) { return (int)((total + t - 1) / t); };

    // zero flag + deg in one memset
    hipMemsetAsync(flagdeg, 0, (N_NODES + 64) * 4, stream);

    // dtype detect + convert (degree count fused)
    k_detect<<<blocks(N_EDGES, T), T, 0, stream>>>((const long long*)ei, flag);
    k_convert<<<blocks(N_EDGES, T), T, 0, stream>>>(ei, flag, epack, deg);

    // 3-kernel exclusive scan -> offs, cursor (dinv fused into scan1)
    k_scan1<<<N_SCAN_BLKS, SCAN_BLK, 0, stream>>>(deg, offs, sums, dinv);
    k_scan2<<<1, SCAN_BLK, 0, stream>>>(sums);
    k_scan3<<<N_SCAN_BLKS, SCAN_BLK, 0, stream>>>(offs, sums, cursor);

    // XCD-sliced CSR fill
    k_fill<<<FILL_CHUNKS * N_SLICES, T, 0, stream>>>(epack, dinv, cursor, csr);

    // y0 = x @ W  (W commutes with propagation; both hops F=40)
    k_linear<<<blocks((long long)N_NODES * (N_CLASSES / 4), T), T, 0, stream>>>(x, W, y0);

    // hop 1: h1 = A_hat @ y0
    k_gather<N_CLASSES, false><<<(N_NODES + 3) / 4, T, 0, stream>>>(offs, csr, y0, dinv, h1, b);
    // hop 2 fused with bias + log_softmax
    k_gather<N_CLASSES, true><<<(N_NODES + 3) / 4, T, 0, stream>>>(offs, csr, h1, dinv, z, b);
}

// Round 7
// 195.885 us; speedup vs baseline: 1.6827x; 1.0493x over previous
//
#include <hip/hip_runtime.h>
#include <hip/hip_fp16.h>
#include <math.h>

#define N_NODES 50000
#define N_EDGES 800000
#define N_FEAT 100
#define N_CLASSES 40
#define N_SLICES 8
#define SLICE_NODES 6250           // N_NODES / N_SLICES exactly
#define FILL_CHUNKS 256
#define FILL_EDGES_PER_CHUNK 3125  // N_EDGES / FILL_CHUNKS exactly
#define SCAN_BLK 256
#define N_SCAN_BLKS ((N_NODES + SCAN_BLK - 1) / SCAN_BLK)  // 196

// ---------------- convert to packed u32 + degree count (dtype decided per wave) ----------------
// For an int32 buffer, a wave's 64 int64-slots are packed id-pairs; at least one
// is >= N_NODES with probability ~1 (needs high-word==0 on ALL 64 to misfire).
// Deterministic for fixed input. N_EDGES % 256 == 0 -> no tail, all lanes live.

__global__ void k_convert(const void* __restrict__ ei,
                          unsigned int* __restrict__ epack, int* __restrict__ deg) {
    int e = blockIdx.x * blockDim.x + threadIdx.x;
    long long v = ((const long long*)ei)[e];
    bool bad = (v < 0 || v >= N_NODES);
    bool is32 = (__ballot(bad) != 0ull);  // wave-uniform
    unsigned int r, c;
    if (is32) {
        const unsigned int* p = (const unsigned int*)ei;
        r = p[e];
        c = p[N_EDGES + e];
    } else {
        r = (unsigned int)v;
        c = (unsigned int)((const long long*)ei)[N_EDGES + e];
    }
    epack[e] = r | (c << 16);
    atomicAdd(&deg[c], 1);  // fire-and-forget
}

// ---------------- 3-kernel exclusive scan: deg -> offs (+ dinv fused) ----------------

__global__ void k_scan1(const int* __restrict__ deg, int* __restrict__ offs,
                        int* __restrict__ sums, float* __restrict__ dinv) {
    __shared__ int s[SCAN_BLK];
    int i = blockIdx.x * SCAN_BLK + threadIdx.x;
    int v = (i < N_NODES) ? deg[i] : 0;
    if (i < N_NODES) dinv[i] = rsqrtf((float)v + 1.0f);  // +1 self-loop
    s[threadIdx.x] = v;
    __syncthreads();
    for (int off = 1; off < SCAN_BLK; off <<= 1) {
        int t = (threadIdx.x >= off) ? s[threadIdx.x - off] : 0;
        __syncthreads();
        s[threadIdx.x] += t;
        __syncthreads();
    }
    if (i < N_NODES) offs[i] = s[threadIdx.x] - v;  // exclusive
    if (threadIdx.x == SCAN_BLK - 1) sums[blockIdx.x] = s[SCAN_BLK - 1];
}

__global__ void k_scan2(int* __restrict__ sums) {
    __shared__ int s[SCAN_BLK];
    int v = (threadIdx.x < N_SCAN_BLKS) ? sums[threadIdx.x] : 0;
    s[threadIdx.x] = v;
    __syncthreads();
    for (int off = 1; off < SCAN_BLK; off <<= 1) {
        int t = (threadIdx.x >= off) ? s[threadIdx.x - off] : 0;
        __syncthreads();
        s[threadIdx.x] += t;
        __syncthreads();
    }
    if (threadIdx.x < N_SCAN_BLKS) sums[threadIdx.x] = s[threadIdx.x] - v;  // exclusive
}

__global__ void k_scan3(int* __restrict__ offs, const int* __restrict__ sums,
                        int* __restrict__ cursor) {
    int i = blockIdx.x * SCAN_BLK + threadIdx.x;
    if (i < N_NODES) {
        int o = offs[i] + sums[blockIdx.x];
        offs[i] = o;
        cursor[i] = o;
    }
    if (i == 0) offs[N_NODES] = N_EDGES;
}

// ---------------- XCD-sliced CSR fill ----------------
// block -> (slice = bid % 8, chunk = bid / 8); bid%8 tracks the round-robin
// block->XCD mapping so each slice's csr/cursor lines are dirtied by ONE XCD.

__global__ void k_fill(const unsigned int* __restrict__ epack, const float* __restrict__ dinv,
                       int* __restrict__ cursor, uint2* __restrict__ csr) {
    int slice = blockIdx.x & (N_SLICES - 1);
    int chunk = blockIdx.x >> 3;
    unsigned int lo = slice * SLICE_NODES, hi = lo + SLICE_NODES;
    int e0 = chunk * FILL_EDGES_PER_CHUNK;
    int e1 = e0 + FILL_EDGES_PER_CHUNK;
    for (int e = e0 + threadIdx.x; e < e1; e += blockDim.x) {
        unsigned int p = epack[e];
        unsigned int c = p >> 16;
        if (c >= lo && c < hi) {
            unsigned int r = p & 0xffffu;
            int pos = atomicAdd(&cursor[c], 1);
            csr[pos] = make_uint2(r, __float_as_uint(dinv[r] * dinv[c]));
        }
    }
}

// ---------------- linear: y0 = x @ W, fp16 out (bias deferred) ----------------

__global__ void k_linear(const float* __restrict__ h, const float* __restrict__ W,
                         __half* __restrict__ y) {
    __shared__ float4 Ws[N_CLASSES / 4][N_FEAT];  // 16 KB
    for (int i = threadIdx.x; i < N_FEAT * (N_CLASSES / 4); i += blockDim.x) {
        int k = i / (N_CLASSES / 4), c4 = i - k * (N_CLASSES / 4);
        Ws[c4][k] = ((const float4*)W)[i];
    }
    __syncthreads();
    int idx = blockIdx.x * blockDim.x + threadIdx.x;
    if (idx >= N_NODES * (N_CLASSES / 4)) return;
    int n = idx / (N_CLASSES / 4);
    int c4 = idx - n * (N_CLASSES / 4);
    const float* hr = h + n * N_FEAT;
    float4 s = {0.f, 0.f, 0.f, 0.f};
#pragma unroll
    for (int k = 0; k < N_FEAT; ++k) {
        float hv = hr[k];
        float4 w = Ws[c4][k];
        s.x += hv * w.x; s.y += hv * w.y; s.z += hv * w.z; s.w += hv * w.w;
    }
    __half2* yo = (__half2*)(y + (size_t)idx * 4);
    yo[0] = __floats2half2_rn(s.x, s.y);
    yo[1] = __floats2half2_rn(s.z, s.w);
}

// ---------------- pull-gather hop over fp16 src ----------------
// one wave per node (lanes 0..39 = classes), 4 nodes per 256-thread block

template <bool LSM, typename DstT>
__global__ void k_gather(const int* __restrict__ offs, const uint2* __restrict__ csr,
                         const __half* __restrict__ src, const float* __restrict__ dinv,
                         DstT* __restrict__ dst, const float* __restrict__ bias) {
    int wave = threadIdx.x >> 6;
    int lane = threadIdx.x & 63;
    int n = blockIdx.x * 4 + wave;
    if (n >= N_NODES) return;
    int s = offs[n], e = offs[n + 1];
    float acc0 = 0.0f, acc1 = 0.0f;
    if (lane < N_CLASSES) {
        float d = dinv[n];
        acc0 = d * d * __half2float(src[(size_t)n * N_CLASSES + lane]);
    }
    int i = s;
    for (; i + 3 < e; i += 4) {
        uint2 e0 = csr[i], e1 = csr[i + 1], e2 = csr[i + 2], e3 = csr[i + 3];
        if (lane < N_CLASSES) {
            float v0 = __half2float(src[(size_t)e0.x * N_CLASSES + lane]);
            float v1 = __half2float(src[(size_t)e1.x * N_CLASSES + lane]);
            float v2 = __half2float(src[(size_t)e2.x * N_CLASSES + lane]);
            float v3 = __half2float(src[(size_t)e3.x * N_CLASSES + lane]);
            acc0 += __uint_as_float(e0.y) * v0;
            acc1 += __uint_as_float(e1.y) * v1;
            acc0 += __uint_as_float(e2.y) * v2;
            acc1 += __uint_as_float(e3.y) * v3;
        }
    }
    for (; i < e; ++i) {
        uint2 e0 = csr[i];
        if (lane < N_CLASSES)
            acc0 += __uint_as_float(e0.y) * __half2float(src[(size_t)e0.x * N_CLASSES + lane]);
    }
    float acc = acc0 + acc1;
    if (!LSM) {
        if (lane < N_CLASSES) {
            if constexpr (sizeof(DstT) == 2)
                dst[(size_t)n * N_CLASSES + lane] = __float2half_rn(acc);
            else
                dst[(size_t)n * N_CLASSES + lane] = acc;
        }
    } else {
        float v = (lane < N_CLASSES) ? acc + bias[lane] : -INFINITY;
        float m = v;
#pragma unroll
        for (int off = 32; off; off >>= 1) m = fmaxf(m, __shfl_xor(m, off));
        float ex = (lane < N_CLASSES) ? __expf(v - m) : 0.0f;
        float ssum = ex;
#pragma unroll
        for (int off = 32; off; off >>= 1) ssum += __shfl_xor(ssum, off);
        float ls = logf(ssum);
        if (lane < N_CLASSES) dst[(size_t)n * N_CLASSES + lane] = (DstT)(v - m - ls);
    }
}

// ---------------- launch ----------------

extern "C" void kernel_launch(void* const* d_in, const int* in_sizes, int n_in,
                              void* d_out, int out_size, void* d_ws, size_t ws_size,
                              hipStream_t stream) {
    const float* x = (const float*)d_in[0];
    const void* ei = d_in[1];                // [2, E], int32 or int64 (wave-local detect)
    const float* W = (const float*)d_in[2];  // [F, C]
    const float* b = (const float*)d_in[3];  // [C]
    float* z = (float*)d_out;                // [N, C]

    // workspace layout (256B-aligned chunks)
    char* ws = (char*)d_ws;
    size_t o = 0;
    auto alloc = [&](size_t bytes) { char* p = ws + o; o += (bytes + 255) & ~(size_t)255; return p; };
    int*          deg    = (int*)alloc(N_NODES * 4);
    unsigned int* epack  = (unsigned int*)alloc((size_t)N_EDGES * 4);
    float*        dinv   = (float*)alloc(N_NODES * 4);
    int*          offs   = (int*)alloc((N_NODES + 1) * 4);
    int*          cursor = (int*)alloc(N_NODES * 4);
    int*          sums   = (int*)alloc(SCAN_BLK * 4);
    uint2*        csr    = (uint2*)alloc((size_t)N_EDGES * 8);
    __half*       y0     = (__half*)alloc((size_t)N_NODES * N_CLASSES * 2);
    __half*       h1     = (__half*)alloc((size_t)N_NODES * N_CLASSES * 2);

    const int T = 256;
    auto blocks = [](long long total, int t) { return (int)((total + t - 1) / t); };

    hipMemsetAsync(deg, 0, N_NODES * 4, stream);

    // convert (dtype ballot + degree count fused)
    k_convert<<<blocks(N_EDGES, T), T, 0, stream>>>(ei, epack, deg);

    // 3-kernel exclusive scan -> offs, cursor (dinv fused into scan1)
    k_scan1<<<N_SCAN_BLKS, SCAN_BLK, 0, stream>>>(deg, offs, sums, dinv);
    k_scan2<<<1, SCAN_BLK, 0, stream>>>(sums);
    k_scan3<<<N_SCAN_BLKS, SCAN_BLK, 0, stream>>>(offs, sums, cursor);

    // XCD-sliced CSR fill
    k_fill<<<FILL_CHUNKS * N_SLICES, T, 0, stream>>>(epack, dinv, cursor, csr);

    // y0 = x @ W (fp16 out; W commutes with propagation; both hops F=40)
    k_linear<<<blocks((long long)N_NODES * (N_CLASSES / 4), T), T, 0, stream>>>(x, W, y0);

    // hop 1: h1 = A_hat @ y0  (fp16 -> fp16)
    k_gather<false, __half><<<(N_NODES + 3) / 4, T, 0, stream>>>(offs, csr, y0, dinv, h1, b);
    // hop 2 fused with bias + log_softmax  (fp16 -> fp32 out)
    k_gather<true, float><<<(N_NODES + 3) / 4, T, 0, stream>>>(offs, csr, h1, dinv, z, b);
}

// Round 8
// 174.534 us; speedup vs baseline: 1.8886x; 1.1223x over previous
//
#include <hip/hip_runtime.h>
#include <hip/hip_fp16.h>
#include <math.h>

#define N_NODES 50000
#define N_EDGES 800000
#define N_FEAT 100
#define N_CLASSES 40
#define N_SLICES 8
#define SLICE_NODES 6250           // N_NODES / N_SLICES exactly
#define FILL_CHUNKS 256
#define FILL_EDGES_PER_CHUNK 3125  // N_EDGES / FILL_CHUNKS exactly
#define SCAN_BLK 256
#define N_SCAN_BLKS ((N_NODES + SCAN_BLK - 1) / SCAN_BLK)  // 196

// ---------------- convert to packed u32 + degree count (dtype decided per wave) ----------------

__global__ void k_convert(const void* __restrict__ ei,
                          unsigned int* __restrict__ epack, int* __restrict__ deg) {
    int e = blockIdx.x * blockDim.x + threadIdx.x;
    long long v = ((const long long*)ei)[e];
    bool bad = (v < 0 || v >= N_NODES);
    bool is32 = (__ballot(bad) != 0ull);  // wave-uniform
    unsigned int r, c;
    if (is32) {
        const unsigned int* p = (const unsigned int*)ei;
        r = p[e];
        c = p[N_EDGES + e];
    } else {
        r = (unsigned int)v;
        c = (unsigned int)((const long long*)ei)[N_EDGES + e];
    }
    epack[e] = r | (c << 16);
    atomicAdd(&deg[c], 1);  // fire-and-forget
}

// ---------------- 3-kernel exclusive scan: deg -> offs (+ dinv fused) ----------------

__global__ void k_scan1(const int* __restrict__ deg, int* __restrict__ offs,
                        int* __restrict__ sums, float* __restrict__ dinv) {
    __shared__ int s[SCAN_BLK];
    int i = blockIdx.x * SCAN_BLK + threadIdx.x;
    int v = (i < N_NODES) ? deg[i] : 0;
    if (i < N_NODES) dinv[i] = rsqrtf((float)v + 1.0f);  // +1 self-loop
    s[threadIdx.x] = v;
    __syncthreads();
    for (int off = 1; off < SCAN_BLK; off <<= 1) {
        int t = (threadIdx.x >= off) ? s[threadIdx.x - off] : 0;
        __syncthreads();
        s[threadIdx.x] += t;
        __syncthreads();
    }
    if (i < N_NODES) offs[i] = s[threadIdx.x] - v;  // exclusive
    if (threadIdx.x == SCAN_BLK - 1) sums[blockIdx.x] = s[SCAN_BLK - 1];
}

__global__ void k_scan2(int* __restrict__ sums) {
    __shared__ int s[SCAN_BLK];
    int v = (threadIdx.x < N_SCAN_BLKS) ? sums[threadIdx.x] : 0;
    s[threadIdx.x] = v;
    __syncthreads();
    for (int off = 1; off < SCAN_BLK; off <<= 1) {
        int t = (threadIdx.x >= off) ? s[threadIdx.x - off] : 0;
        __syncthreads();
        s[threadIdx.x] += t;
        __syncthreads();
    }
    if (threadIdx.x < N_SCAN_BLKS) sums[threadIdx.x] = s[threadIdx.x] - v;  // exclusive
}

__global__ void k_scan3(int* __restrict__ offs, const int* __restrict__ sums,
                        int* __restrict__ cursor) {
    int i = blockIdx.x * SCAN_BLK + threadIdx.x;
    if (i < N_NODES) {
        int o = offs[i] + sums[blockIdx.x];
        offs[i] = o;
        cursor[i] = o;
    }
    if (i == 0) offs[N_NODES] = N_EDGES;
}

// ---------------- XCD-sliced CSR fill ----------------

__global__ void k_fill(const unsigned int* __restrict__ epack, const float* __restrict__ dinv,
                       int* __restrict__ cursor, uint2* __restrict__ csr) {
    int slice = blockIdx.x & (N_SLICES - 1);
    int chunk = blockIdx.x >> 3;
    unsigned int lo = slice * SLICE_NODES, hi = lo + SLICE_NODES;
    int e0 = chunk * FILL_EDGES_PER_CHUNK;
    int e1 = e0 + FILL_EDGES_PER_CHUNK;
    for (int e = e0 + threadIdx.x; e < e1; e += blockDim.x) {
        unsigned int p = epack[e];
        unsigned int c = p >> 16;
        if (c >= lo && c < hi) {
            unsigned int r = p & 0xffffu;
            int pos = atomicAdd(&cursor[c], 1);
            csr[pos] = make_uint2(r, __float_as_uint(dinv[r] * dinv[c]));
        }
    }
}

// ---------------- linear: y0 = x @ W, fp16 out (bias deferred) ----------------

__global__ void k_linear(const float* __restrict__ h, const float* __restrict__ W,
                         __half* __restrict__ y) {
    __shared__ float4 Ws[N_CLASSES / 4][N_FEAT];  // 16 KB
    for (int i = threadIdx.x; i < N_FEAT * (N_CLASSES / 4); i += blockDim.x) {
        int k = i / (N_CLASSES / 4), c4 = i - k * (N_CLASSES / 4);
        Ws[c4][k] = ((const float4*)W)[i];
    }
    __syncthreads();
    int idx = blockIdx.x * blockDim.x + threadIdx.x;
    if (idx >= N_NODES * (N_CLASSES / 4)) return;
    int n = idx / (N_CLASSES / 4);
    int c4 = idx - n * (N_CLASSES / 4);
    const float* hr = h + n * N_FEAT;
    float4 s = {0.f, 0.f, 0.f, 0.f};
#pragma unroll
    for (int k = 0; k < N_FEAT; ++k) {
        float hv = hr[k];
        float4 w = Ws[c4][k];
        s.x += hv * w.x; s.y += hv * w.y; s.z += hv * w.z; s.w += hv * w.w;
    }
    __half2* yo = (__half2*)(y + (size_t)idx * 4);
    yo[0] = __floats2half2_rn(s.x, s.y);
    yo[1] = __floats2half2_rn(s.z, s.w);
}

// ---------------- pull-gather hop over fp16 src, 8-deep MLP ----------------
// one wave per node (lanes 0..39 = classes), 4 nodes per 256-thread block

template <bool LSM, typename DstT>
__global__ void k_gather(const int* __restrict__ offs, const uint2* __restrict__ csr,
                         const __half* __restrict__ src, const float* __restrict__ dinv,
                         DstT* __restrict__ dst, const float* __restrict__ bias) {
    int wave = threadIdx.x >> 6;
    int lane = threadIdx.x & 63;
    int n = blockIdx.x * 4 + wave;
    if (n >= N_NODES) return;
    int s = offs[n], e = offs[n + 1];
    bool act = (lane < N_CLASSES);
    const __half* sl = src + lane;  // per-lane base; addr = sl + 40*r
    float acc0 = 0.0f, acc1 = 0.0f, acc2 = 0.0f, acc3 = 0.0f;
    if (act) {
        float d = dinv[n];
        acc0 = d * d * __half2float(sl[(size_t)n * N_CLASSES]);
    }
    int i = s;
    // peel to even index so uint4 loads are 16B-aligned
    if ((i & 1) && i < e) {
        uint2 q = csr[i];
        if (act) acc1 += __uint_as_float(q.y) * __half2float(sl[(size_t)q.x * N_CLASSES]);
        ++i;
    }
    for (; i + 7 < e; i += 8) {
        uint4 q0 = *(const uint4*)(csr + i);
        uint4 q1 = *(const uint4*)(csr + i + 2);
        uint4 q2 = *(const uint4*)(csr + i + 4);
        uint4 q3 = *(const uint4*)(csr + i + 6);
        if (act) {
            float v0 = __half2float(sl[(size_t)q0.x * N_CLASSES]);
            float v1 = __half2float(sl[(size_t)q0.z * N_CLASSES]);
            float v2 = __half2float(sl[(size_t)q1.x * N_CLASSES]);
            float v3 = __half2float(sl[(size_t)q1.z * N_CLASSES]);
            float v4 = __half2float(sl[(size_t)q2.x * N_CLASSES]);
            float v5 = __half2float(sl[(size_t)q2.z * N_CLASSES]);
            float v6 = __half2float(sl[(size_t)q3.x * N_CLASSES]);
            float v7 = __half2float(sl[(size_t)q3.z * N_CLASSES]);
            acc0 += __uint_as_float(q0.y) * v0;
            acc1 += __uint_as_float(q0.w) * v1;
            acc2 += __uint_as_float(q1.y) * v2;
            acc3 += __uint_as_float(q1.w) * v3;
            acc0 += __uint_as_float(q2.y) * v4;
            acc1 += __uint_as_float(q2.w) * v5;
            acc2 += __uint_as_float(q3.y) * v6;
            acc3 += __uint_as_float(q3.w) * v7;
        }
    }
    for (; i + 1 < e; i += 2) {
        uint4 q0 = *(const uint4*)(csr + i);
        if (act) {
            float v0 = __half2float(sl[(size_t)q0.x * N_CLASSES]);
            float v1 = __half2float(sl[(size_t)q0.z * N_CLASSES]);
            acc0 += __uint_as_float(q0.y) * v0;
            acc1 += __uint_as_float(q0.w) * v1;
        }
    }
    if (i < e) {
        uint2 q = csr[i];
        if (act) acc2 += __uint_as_float(q.y) * __half2float(sl[(size_t)q.x * N_CLASSES]);
    }
    float acc = (acc0 + acc1) + (acc2 + acc3);
    if (!LSM) {
        if (act) {
            if constexpr (sizeof(DstT) == 2)
                dst[(size_t)n * N_CLASSES + lane] = __float2half_rn(acc);
            else
                dst[(size_t)n * N_CLASSES + lane] = acc;
        }
    } else {
        float v = act ? acc + bias[lane] : -INFINITY;
        float m = v;
#pragma unroll
        for (int off = 32; off; off >>= 1) m = fmaxf(m, __shfl_xor(m, off));
        float ex = act ? __expf(v - m) : 0.0f;
        float ssum = ex;
#pragma unroll
        for (int off = 32; off; off >>= 1) ssum += __shfl_xor(ssum, off);
        float ls = logf(ssum);
        if (act) dst[(size_t)n * N_CLASSES + lane] = (DstT)(v - m - ls);
    }
}

// ---------------- launch ----------------

extern "C" void kernel_launch(void* const* d_in, const int* in_sizes, int n_in,
                              void* d_out, int out_size, void* d_ws, size_t ws_size,
                              hipStream_t stream) {
    const float* x = (const float*)d_in[0];
    const void* ei = d_in[1];                // [2, E], int32 or int64 (wave-local detect)
    const float* W = (const float*)d_in[2];  // [F, C]
    const float* b = (const float*)d_in[3];  // [C]
    float* z = (float*)d_out;                // [N, C]

    // workspace layout (256B-aligned chunks)
    char* ws = (char*)d_ws;
    size_t o = 0;
    auto alloc = [&](size_t bytes) { char* p = ws + o; o += (bytes + 255) & ~(size_t)255; return p; };
    int*          deg    = (int*)alloc(N_NODES * 4);
    unsigned int* epack  = (unsigned int*)alloc((size_t)N_EDGES * 4);
    float*        dinv   = (float*)alloc(N_NODES * 4);
    int*          offs   = (int*)alloc((N_NODES + 1) * 4);
    int*          cursor = (int*)alloc(N_NODES * 4);
    int*          sums   = (int*)alloc(SCAN_BLK * 4);
    uint2*        csr    = (uint2*)alloc((size_t)N_EDGES * 8);
    __half*       y0     = (__half*)alloc((size_t)N_NODES * N_CLASSES * 2);
    __half*       h1     = (__half*)alloc((size_t)N_NODES * N_CLASSES * 2);

    const int T = 256;
    auto blocks = [](long long total, int t) { return (int)((total + t - 1) / t); };

    hipMemsetAsync(deg, 0, N_NODES * 4, stream);

    // convert (dtype ballot + degree count fused)
    k_convert<<<blocks(N_EDGES, T), T, 0, stream>>>(ei, epack, deg);

    // 3-kernel exclusive scan -> offs, cursor (dinv fused into scan1)
    k_scan1<<<N_SCAN_BLKS, SCAN_BLK, 0, stream>>>(deg, offs, sums, dinv);
    k_scan2<<<1, SCAN_BLK, 0, stream>>>(sums);
    k_scan3<<<N_SCAN_BLKS, SCAN_BLK, 0, stream>>>(offs, sums, cursor);

    // XCD-sliced CSR fill
    k_fill<<<FILL_CHUNKS * N_SLICES, T, 0, stream>>>(epack, dinv, cursor, csr);

    // y0 = x @ W (fp16 out; W commutes with propagation; both hops F=40)
    k_linear<<<blocks((long long)N_NODES * (N_CLASSES / 4), T), T, 0, stream>>>(x, W, y0);

    // hop 1: h1 = A_hat @ y0  (fp16 -> fp16)
    k_gather<false, __half><<<(N_NODES + 3) / 4, T, 0, stream>>>(offs, csr, y0, dinv, h1, b);
    // hop 2 fused with bias + log_softmax  (fp16 -> fp32 out)
    k_gather<true, float><<<(N_NODES + 3) / 4, T, 0, stream>>>(offs, csr, h1, dinv, z, b);
}

// Round 9
// 173.751 us; speedup vs baseline: 1.8971x; 1.0045x over previous
//
#include <hip/hip_runtime.h>
#include <hip/hip_fp16.h>
#include <math.h>

#define N_NODES 50000
#define N_EDGES 800000
#define N_FEAT 100
#define N_CLASSES 40
#define N_SLICES 8
#define SLICE_NODES 6250           // N_NODES / N_SLICES exactly
#define FILL_CHUNKS 256
#define FILL_EDGES_PER_CHUNK 3125  // N_EDGES / FILL_CHUNKS exactly
#define SCAN_BLK 256
#define N_SCAN_BLKS ((N_NODES + SCAN_BLK - 1) / SCAN_BLK)  // 196

// ---------------- zero deg (replaces 42us rocclr fillBuffer) ----------------
// 50000 ints = 12500 uint4; grid 49 x 256

__global__ void k_zero(uint4* __restrict__ p, int n4) {
    int i = blockIdx.x * blockDim.x + threadIdx.x;
    if (i < n4) p[i] = make_uint4(0u, 0u, 0u, 0u);
}

// ---------------- convert to packed u32 + degree count (dtype decided per wave) ----------------

__global__ void k_convert(const void* __restrict__ ei,
                          unsigned int* __restrict__ epack, int* __restrict__ deg) {
    int e = blockIdx.x * blockDim.x + threadIdx.x;
    long long v = ((const long long*)ei)[e];
    bool bad = (v < 0 || v >= N_NODES);
    bool is32 = (__ballot(bad) != 0ull);  // wave-uniform
    unsigned int r, c;
    if (is32) {
        const unsigned int* p = (const unsigned int*)ei;
        r = p[e];
        c = p[N_EDGES + e];
    } else {
        r = (unsigned int)v;
        c = (unsigned int)((const long long*)ei)[N_EDGES + e];
    }
    epack[e] = r | (c << 16);
    atomicAdd(&deg[c], 1);  // fire-and-forget
}

// ---------------- 3-kernel exclusive scan: deg -> offs (+ dinv fused) ----------------

__global__ void k_scan1(const int* __restrict__ deg, int* __restrict__ offs,
                        int* __restrict__ sums, float* __restrict__ dinv) {
    __shared__ int s[SCAN_BLK];
    int i = blockIdx.x * SCAN_BLK + threadIdx.x;
    int v = (i < N_NODES) ? deg[i] : 0;
    if (i < N_NODES) dinv[i] = rsqrtf((float)v + 1.0f);  // +1 self-loop
    s[threadIdx.x] = v;
    __syncthreads();
    for (int off = 1; off < SCAN_BLK; off <<= 1) {
        int t = (threadIdx.x >= off) ? s[threadIdx.x - off] : 0;
        __syncthreads();
        s[threadIdx.x] += t;
        __syncthreads();
    }
    if (i < N_NODES) offs[i] = s[threadIdx.x] - v;  // exclusive
    if (threadIdx.x == SCAN_BLK - 1) sums[blockIdx.x] = s[SCAN_BLK - 1];
}

__global__ void k_scan2(int* __restrict__ sums) {
    __shared__ int s[SCAN_BLK];
    int v = (threadIdx.x < N_SCAN_BLKS) ? sums[threadIdx.x] : 0;
    s[threadIdx.x] = v;
    __syncthreads();
    for (int off = 1; off < SCAN_BLK; off <<= 1) {
        int t = (threadIdx.x >= off) ? s[threadIdx.x - off] : 0;
        __syncthreads();
        s[threadIdx.x] += t;
        __syncthreads();
    }
    if (threadIdx.x < N_SCAN_BLKS) sums[threadIdx.x] = s[threadIdx.x] - v;  // exclusive
}

__global__ void k_scan3(int* __restrict__ offs, const int* __restrict__ sums,
                        int* __restrict__ cursor) {
    int i = blockIdx.x * SCAN_BLK + threadIdx.x;
    if (i < N_NODES) {
        int o = offs[i] + sums[blockIdx.x];
        offs[i] = o;
        cursor[i] = o;
    }
    if (i == 0) offs[N_NODES] = N_EDGES;
}

// ---------------- XCD-sliced CSR fill ----------------

__global__ void k_fill(const unsigned int* __restrict__ epack, const float* __restrict__ dinv,
                       int* __restrict__ cursor, uint2* __restrict__ csr) {
    int slice = blockIdx.x & (N_SLICES - 1);
    int chunk = blockIdx.x >> 3;
    unsigned int lo = slice * SLICE_NODES, hi = lo + SLICE_NODES;
    int e0 = chunk * FILL_EDGES_PER_CHUNK;
    int e1 = e0 + FILL_EDGES_PER_CHUNK;
    for (int e = e0 + threadIdx.x; e < e1; e += blockDim.x) {
        unsigned int p = epack[e];
        unsigned int c = p >> 16;
        if (c >= lo && c < hi) {
            unsigned int r = p & 0xffffu;
            int pos = atomicAdd(&cursor[c], 1);
            csr[pos] = make_uint2(r, __float_as_uint(dinv[r] * dinv[c]));
        }
    }
}

// ---------------- linear: y0 = x @ W, fp16 out (bias deferred) ----------------

__global__ void k_linear(const float* __restrict__ h, const float* __restrict__ W,
                         __half* __restrict__ y) {
    __shared__ float4 Ws[N_CLASSES / 4][N_FEAT];  // 16 KB
    for (int i = threadIdx.x; i < N_FEAT * (N_CLASSES / 4); i += blockDim.x) {
        int k = i / (N_CLASSES / 4), c4 = i - k * (N_CLASSES / 4);
        Ws[c4][k] = ((const float4*)W)[i];
    }
    __syncthreads();
    int idx = blockIdx.x * blockDim.x + threadIdx.x;
    if (idx >= N_NODES * (N_CLASSES / 4)) return;
    int n = idx / (N_CLASSES / 4);
    int c4 = idx - n * (N_CLASSES / 4);
    const float* hr = h + n * N_FEAT;
    float4 s = {0.f, 0.f, 0.f, 0.f};
#pragma unroll
    for (int k = 0; k < N_FEAT; ++k) {
        float hv = hr[k];
        float4 w = Ws[c4][k];
        s.x += hv * w.x; s.y += hv * w.y; s.z += hv * w.z; s.w += hv * w.w;
    }
    __half2* yo = (__half2*)(y + (size_t)idx * 4);
    yo[0] = __floats2half2_rn(s.x, s.y);
    yo[1] = __floats2half2_rn(s.z, s.w);
}

// ---------------- pull-gather hop over fp16 src, 8-deep MLP ----------------
// one wave per node (lanes 0..39 = classes), 4 nodes per 256-thread block

template <bool LSM, typename DstT>
__global__ void k_gather(const int* __restrict__ offs, const uint2* __restrict__ csr,
                         const __half* __restrict__ src, const float* __restrict__ dinv,
                         DstT* __restrict__ dst, const float* __restrict__ bias) {
    int wave = threadIdx.x >> 6;
    int lane = threadIdx.x & 63;
    int n = blockIdx.x * 4 + wave;
    if (n >= N_NODES) return;
    int s = offs[n], e = offs[n + 1];
    bool act = (lane < N_CLASSES);
    const __half* sl = src + lane;  // per-lane base; addr = sl + 40*r
    float acc0 = 0.0f, acc1 = 0.0f, acc2 = 0.0f, acc3 = 0.0f;
    if (act) {
        float d = dinv[n];
        acc0 = d * d * __half2float(sl[(size_t)n * N_CLASSES]);
    }
    int i = s;
    // peel to even index so uint4 loads are 16B-aligned
    if ((i & 1) && i < e) {
        uint2 q = csr[i];
        if (act) acc1 += __uint_as_float(q.y) * __half2float(sl[(size_t)q.x * N_CLASSES]);
        ++i;
    }
    for (; i + 7 < e; i += 8) {
        uint4 q0 = *(const uint4*)(csr + i);
        uint4 q1 = *(const uint4*)(csr + i + 2);
        uint4 q2 = *(const uint4*)(csr + i + 4);
        uint4 q3 = *(const uint4*)(csr + i + 6);
        if (act) {
            float v0 = __half2float(sl[(size_t)q0.x * N_CLASSES]);
            float v1 = __half2float(sl[(size_t)q0.z * N_CLASSES]);
            float v2 = __half2float(sl[(size_t)q1.x * N_CLASSES]);
            float v3 = __half2float(sl[(size_t)q1.z * N_CLASSES]);
            float v4 = __half2float(sl[(size_t)q2.x * N_CLASSES]);
            float v5 = __half2float(sl[(size_t)q2.z * N_CLASSES]);
            float v6 = __half2float(sl[(size_t)q3.x * N_CLASSES]);
            float v7 = __half2float(sl[(size_t)q3.z * N_CLASSES]);
            acc0 += __uint_as_float(q0.y) * v0;
            acc1 += __uint_as_float(q0.w) * v1;
            acc2 += __uint_as_float(q1.y) * v2;
            acc3 += __uint_as_float(q1.w) * v3;
            acc0 += __uint_as_float(q2.y) * v4;
            acc1 += __uint_as_float(q2.w) * v5;
            acc2 += __uint_as_float(q3.y) * v6;
            acc3 += __uint_as_float(q3.w) * v7;
        }
    }
    for (; i + 1 < e; i += 2) {
        uint4 q0 = *(const uint4*)(csr + i);
        if (act) {
            float v0 = __half2float(sl[(size_t)q0.x * N_CLASSES]);
            float v1 = __half2float(sl[(size_t)q0.z * N_CLASSES]);
            acc0 += __uint_as_float(q0.y) * v0;
            acc1 += __uint_as_float(q0.w) * v1;
        }
    }
    if (i < e) {
        uint2 q = csr[i];
        if (act) acc2 += __uint_as_float(q.y) * __half2float(sl[(size_t)q.x * N_CLASSES]);
    }
    float acc = (acc0 + acc1) + (acc2 + acc3);
    if (!LSM) {
        if (act) {
            if constexpr (sizeof(DstT) == 2)
                dst[(size_t)n * N_CLASSES + lane] = __float2half_rn(acc);
            else
                dst[(size_t)n * N_CLASSES + lane] = acc;
        }
    } else {
        float v = act ? acc + bias[lane] : -INFINITY;
        float m = v;
#pragma unroll
        for (int off = 32; off; off >>= 1) m = fmaxf(m, __shfl_xor(m, off));
        float ex = act ? __expf(v - m) : 0.0f;
        float ssum = ex;
#pragma unroll
        for (int off = 32; off; off >>= 1) ssum += __shfl_xor(ssum, off);
        float ls = logf(ssum);
        if (act) dst[(size_t)n * N_CLASSES + lane] = (DstT)(v - m - ls);
    }
}

// ---------------- launch ----------------

extern "C" void kernel_launch(void* const* d_in, const int* in_sizes, int n_in,
                              void* d_out, int out_size, void* d_ws, size_t ws_size,
                              hipStream_t stream) {
    const float* x = (const float*)d_in[0];
    const void* ei = d_in[1];                // [2, E], int32 or int64 (wave-local detect)
    const float* W = (const float*)d_in[2];  // [F, C]
    const float* b = (const float*)d_in[3];  // [C]
    float* z = (float*)d_out;                // [N, C]

    // workspace layout (256B-aligned chunks)
    char* ws = (char*)d_ws;
    size_t o = 0;
    auto alloc = [&](size_t bytes) { char* p = ws + o; o += (bytes + 255) & ~(size_t)255; return p; };
    int*          deg    = (int*)alloc(N_NODES * 4);        // 50000 (12500 uint4)
    unsigned int* epack  = (unsigned int*)alloc((size_t)N_EDGES * 4);
    float*        dinv   = (float*)alloc(N_NODES * 4);
    int*          offs   = (int*)alloc((N_NODES + 1) * 4);
    int*          cursor = (int*)alloc(N_NODES * 4);
    int*          sums   = (int*)alloc(SCAN_BLK * 4);
    uint2*        csr    = (uint2*)alloc((size_t)N_EDGES * 8);
    __half*       y0     = (__half*)alloc((size_t)N_NODES * N_CLASSES * 2);
    __half*       h1     = (__half*)alloc((size_t)N_NODES * N_CLASSES * 2);

    const int T = 256;
    auto blocks = [](long long total, int t) { return (int)((total + t - 1) / t); };

    // zero deg with a proper kernel (rocclr fillBuffer ran at 5 GB/s = 42us)
    k_zero<<<blocks(N_NODES / 4 + 1, T), T, 0, stream>>>((uint4*)deg, 12500);

    // convert (dtype ballot + degree count fused)
    k_convert<<<blocks(N_EDGES, T), T, 0, stream>>>(ei, epack, deg);

    // 3-kernel exclusive scan -> offs, cursor (dinv fused into scan1)
    k_scan1<<<N_SCAN_BLKS, SCAN_BLK, 0, stream>>>(deg, offs, sums, dinv);
    k_scan2<<<1, SCAN_BLK, 0, stream>>>(sums);
    k_scan3<<<N_SCAN_BLKS, SCAN_BLK, 0, stream>>>(offs, sums, cursor);

    // XCD-sliced CSR fill
    k_fill<<<FILL_CHUNKS * N_SLICES, T, 0, stream>>>(epack, dinv, cursor, csr);

    // y0 = x @ W (fp16 out; W commutes with propagation; both hops F=40)
    k_linear<<<blocks((long long)N_NODES * (N_CLASSES / 4), T), T, 0, stream>>>(x, W, y0);

    // hop 1: h1 = A_hat @ y0  (fp16 -> fp16)
    k_gather<false, __half><<<(N_NODES + 3) / 4, T, 0, stream>>>(offs, csr, y0, dinv, h1, b);
    // hop 2 fused with bias + log_softmax  (fp16 -> fp32 out)
    k_gather<true, float><<<(N_NODES + 3) / 4, T, 0, stream>>>(offs, csr, h1, dinv, z, b);
}